// Round 3
// baseline (774.888 us; speedup 1.0000x reference)
//
#include <hip/hip_runtime.h>
#include <hip/hip_cooperative_groups.h>

namespace cg = cooperative_groups;

// WaveCell round-9: ONE cooperative launch, 16 phases x 16 steps, grid.sync()
// between phases. Rounds 7-8 showed per-step work changes are invisible
// (~20 us/launch slot vs ~4-6 us estimated exec): the time is inter-kernel
// overhead (launch latency + per-boundary L2 writeback/invalidate across 8
// XCDs + per-launch prologue reload/recompute). grid.sync() provides the
// same agent-scope release/acquire (wbl2/inv) visibility a kernel boundary
// gave, paid in-kernel, and lets us hoist all loop-invariant setup
// (c/b loads, coefficient fusion, source mask) out of the 16 phases.
// Fallback: same kernel launched 16x classically if coop launch fails
// (the sync only executes for phases after the first within one launch).
// Carried: fused 7-op cell, trapezoid row-gating, lgkm-only step barriers,
// pipelined output stores, masked lg==7 shuffle.

#define NXg 192
#define NYg 192
#define BATCH 4
#define TSTEPS 256
#define CELLS (NXg * NYg)

#define TS 24                   // output tile side
#define KSTEP 16                // time steps per phase
#define EXT 56                  // TS + 2*KSTEP
#define LROWS (EXT + 2)         // rows 1..56 used; 0/57 never read
#define LPITCH 68               // dwords/row: 4 pad | 56 data | 8 pad
#define LSZ (LROWS * LPITCH)
#define NTHREADS 448            // 56 rows x 8 lanes/row = 7 waves

#define SRC_X 96
#define SRC_Y 32

__global__ __launch_bounds__(NTHREADS) void wave_kernel(
    const float* __restrict__ cgp, const float* __restrict__ bgp,
    const float* __restrict__ x, float* __restrict__ out,
    int t0b, int t0e) {
  __shared__ float buf0[LSZ];
  __shared__ float buf1[LSZ];
  cg::grid_group grid = cg::this_grid();

  const int tid = threadIdx.x;
  const int lr = tid >> 3;      // local row 0..55
  const int lg = tid & 7;       // 8-wide group in row; lg==7 is the zero lane
  const int bcol = blockIdx.x;  // 0..7
  const int brow = blockIdx.y;  // 0..7
  const int bb = blockIdx.z;    // 0..3
  const int r0 = brow * TS - KSTEP;
  const int c0 = bcol * TS - KSTEP;
  const int obase = bb * TSTEPS * CELLS;
  const float inv_h2 = (float)(1.0 / (2.0 * 1.01 * 1.01 * 1.0e-3 * 1.0e-3));

  const int gr = r0 + lr;
  const int gc = c0 + 8 * lg;  // multiple of 8; never straddles domain edge
  const bool id = (lg < 7) && (gr >= 0) && (gr < NXg) && (gc >= 0) && (gc < NYg);
  const bool til = (lr >= KSTEP) && (lr < KSTEP + TS) && (lg >= 2) && (lg < 5);
  const bool hs = (SRC_X >= r0) && (SRC_X < r0 + EXT) &&
                  (SRC_Y >= c0) && (SRC_Y < c0 + EXT);
  const int gofs = id ? (gr * NYg + gc) : 0;

  const float4 z4 = make_float4(0.f, 0.f, 0.f, 0.f);

  // ---- Loop-invariant: c/b loads + fused coefficients + source mask. ----
  // val = Dc*yc - Ey*yp + G*(sum4 - 4*yc) [+ sm*xt]
  // !id lanes keep Dc=Ey=G=0 -> val identically 0 (zero padding / zero lane).
  float4 Dc0 = z4, Dc1 = z4, Ey0 = z4, Ey1 = z4, G0 = z4, G1 = z4;
  float4 sm0 = z4, sm1 = z4;
  if (id) {
    float4 cv0 = *(const float4*)(cgp + gofs);
    float4 cv1 = *(const float4*)(cgp + gofs + 4);
    float4 bv0 = *(const float4*)(bgp + gofs);
    float4 bv1 = *(const float4*)(bgp + gofs + 4);
    float ai;
    ai = 1.0f / (1.0e6f + 500.0f * bv0.x);
    Dc0.x = 2.0e6f * ai; Ey0.x = (1.0e6f - 500.0f * bv0.x) * ai;
    G0.x = (cv0.x * cv0.x) * inv_h2 * ai;
    ai = 1.0f / (1.0e6f + 500.0f * bv0.y);
    Dc0.y = 2.0e6f * ai; Ey0.y = (1.0e6f - 500.0f * bv0.y) * ai;
    G0.y = (cv0.y * cv0.y) * inv_h2 * ai;
    ai = 1.0f / (1.0e6f + 500.0f * bv0.z);
    Dc0.z = 2.0e6f * ai; Ey0.z = (1.0e6f - 500.0f * bv0.z) * ai;
    G0.z = (cv0.z * cv0.z) * inv_h2 * ai;
    ai = 1.0f / (1.0e6f + 500.0f * bv0.w);
    Dc0.w = 2.0e6f * ai; Ey0.w = (1.0e6f - 500.0f * bv0.w) * ai;
    G0.w = (cv0.w * cv0.w) * inv_h2 * ai;
    ai = 1.0f / (1.0e6f + 500.0f * bv1.x);
    Dc1.x = 2.0e6f * ai; Ey1.x = (1.0e6f - 500.0f * bv1.x) * ai;
    G1.x = (cv1.x * cv1.x) * inv_h2 * ai;
    ai = 1.0f / (1.0e6f + 500.0f * bv1.y);
    Dc1.y = 2.0e6f * ai; Ey1.y = (1.0e6f - 500.0f * bv1.y) * ai;
    G1.y = (cv1.y * cv1.y) * inv_h2 * ai;
    ai = 1.0f / (1.0e6f + 500.0f * bv1.z);
    Dc1.z = 2.0e6f * ai; Ey1.z = (1.0e6f - 500.0f * bv1.z) * ai;
    G1.z = (cv1.z * cv1.z) * inv_h2 * ai;
    ai = 1.0f / (1.0e6f + 500.0f * bv1.w);
    Dc1.w = 2.0e6f * ai; Ey1.w = (1.0e6f - 500.0f * bv1.w) * ai;
    G1.w = (cv1.w * cv1.w) * inv_h2 * ai;
    if (gr == SRC_X) {
      sm0.x = (gc + 0 == SRC_Y) ? 1.0f : 0.0f;
      sm0.y = (gc + 1 == SRC_Y) ? 1.0f : 0.0f;
      sm0.z = (gc + 2 == SRC_Y) ? 1.0f : 0.0f;
      sm0.w = (gc + 3 == SRC_Y) ? 1.0f : 0.0f;
      sm1.x = (gc + 4 == SRC_Y) ? 1.0f : 0.0f;
      sm1.y = (gc + 5 == SRC_Y) ? 1.0f : 0.0f;
      sm1.z = (gc + 6 == SRC_Y) ? 1.0f : 0.0f;
      sm1.w = (gc + 7 == SRC_Y) ? 1.0f : 0.0f;
    }
  }

  const int lo = (lr + 1) * LPITCH + 4 + 8 * lg;

#define CELL(dst, up_, dn_, lf_, rt_, D_, E_, Gc_, y_, p_)              \
  {                                                                     \
    float s_ = fmaf(-4.0f, y_, (up_ + dn_) + (lf_ + rt_));              \
    dst = fmaf(Gc_, s_, fmaf(-E_, p_, D_ * y_));                        \
  }

  for (int t0 = t0b; t0 < t0e; t0 += KSTEP) {
    if (t0 > t0b) {
      // Release(own pv stores, vmcnt-drained) + acquire(others' stores,
      // L2 inv) at agent scope -- replaces a kernel boundary.
      grid.sync();
    }

    // ---- Per-phase state reload (halo-extended region, 2 time slices). ----
    float4 yc0 = z4, yc1 = z4, yp0 = z4, yp1 = z4;
    if (id && t0 > 0) {
      yc0 = *(const float4*)(out + obase + (t0 - 1) * CELLS + gofs);
      yc1 = *(const float4*)(out + obase + (t0 - 1) * CELLS + gofs + 4);
      yp0 = *(const float4*)(out + obase + (t0 - 2) * CELLS + gofs);
      yp1 = *(const float4*)(out + obase + (t0 - 2) * CELLS + gofs + 4);
    }
    float xs[KSTEP];
    {
      const float4* xp = (const float4*)(x + bb * TSTEPS + t0);
      float4 a0 = xp[0], a1 = xp[1], a2 = xp[2], a3 = xp[3];
      xs[0] = a0.x; xs[1] = a0.y; xs[2] = a0.z; xs[3] = a0.w;
      xs[4] = a1.x; xs[5] = a1.y; xs[6] = a1.z; xs[7] = a1.w;
      xs[8] = a2.x; xs[9] = a2.y; xs[10] = a2.z; xs[11] = a2.w;
      xs[12] = a3.x; xs[13] = a3.y; xs[14] = a3.z; xs[15] = a3.w;
    }

    // Scatter y(t-1) into buf0 rows 1..56 (guard rows never read).
    *(float4*)&buf0[lo] = yc0;
    *(float4*)&buf0[lo + 4] = yc1;
    asm volatile("s_waitcnt lgkmcnt(0)\n\ts_barrier" ::: "memory");

    float* ping = buf0;
    float* pong = buf1;

    float4 pv0 = z4, pv1 = z4;
    float* pop = out;  // dummy; only used when j>0

#pragma unroll
    for (int j = 0; j < KSTEP; ++j) {
      const float xt = xs[j];
      float* op = out + obase + (t0 + j) * CELLS;

      // Store PREVIOUS step's output now; never drained inside the loop
      // (lgkm-only barriers), retires by the next grid.sync / kernel end.
      if (j > 0 && til) {
        *(float4*)(pop + gofs) = pv0;
        *(float4*)(pop + gofs + 4) = pv1;
      }

      // Trapezoid gating: step j only needs rows [j+1, 54-j]; j is
      // compile-time (full unroll) -> dead waves skip via execz.
      const bool alive = (lr >= j + 1) && (lr <= 54 - j);
      if (alive) {
        float lqw = __shfl_up(yc1.w, 1);
        lqw = (lg == 0) ? 0.0f : lqw;       // row's left edge neighbor is 0
        float rqx = __shfl_down(yc0.x, 1);  // lg==6 pulls zero lane -> 0
        rqx = (lg == 7) ? 0.0f : rqx;       // source lane may be exec-masked

        float4 up0 = *(float4*)&ping[lo - LPITCH];
        float4 up1 = *(float4*)&ping[lo - LPITCH + 4];
        float4 dn0 = *(float4*)&ping[lo + LPITCH];
        float4 dn1 = *(float4*)&ping[lo + LPITCH + 4];

        float4 val0, val1;
        CELL(val0.x, up0.x, dn0.x, lqw,    yc0.y, Dc0.x, Ey0.x, G0.x, yc0.x, yp0.x);
        CELL(val0.y, up0.y, dn0.y, yc0.x,  yc0.z, Dc0.y, Ey0.y, G0.y, yc0.y, yp0.y);
        CELL(val0.z, up0.z, dn0.z, yc0.y,  yc0.w, Dc0.z, Ey0.z, G0.z, yc0.z, yp0.z);
        CELL(val0.w, up0.w, dn0.w, yc0.z,  yc1.x, Dc0.w, Ey0.w, G0.w, yc0.w, yp0.w);
        CELL(val1.x, up1.x, dn1.x, yc0.w,  yc1.y, Dc1.x, Ey1.x, G1.x, yc1.x, yp1.x);
        CELL(val1.y, up1.y, dn1.y, yc1.x,  yc1.z, Dc1.y, Ey1.y, G1.y, yc1.y, yp1.y);
        CELL(val1.z, up1.z, dn1.z, yc1.y,  yc1.w, Dc1.z, Ey1.z, G1.z, yc1.z, yp1.z);
        CELL(val1.w, up1.w, dn1.w, yc1.z,  rqx,   Dc1.w, Ey1.w, G1.w, yc1.w, yp1.w);

        if (hs) {  // uniform: only blocks whose EXT tile contains the source
          val0.x = fmaf(sm0.x, xt, val0.x);
          val0.y = fmaf(sm0.y, xt, val0.y);
          val0.z = fmaf(sm0.z, xt, val0.z);
          val0.w = fmaf(sm0.w, xt, val0.w);
          val1.x = fmaf(sm1.x, xt, val1.x);
          val1.y = fmaf(sm1.y, xt, val1.y);
          val1.z = fmaf(sm1.z, xt, val1.z);
          val1.w = fmaf(sm1.w, xt, val1.w);
        }

        yp0 = yc0; yp1 = yc1;
        yc0 = val0; yc1 = val1;

        if (j < KSTEP - 1) {           // final step's LDS state never read
          *(float4*)&pong[lo] = val0;  // lg==7 writes 0 into right pad
          *(float4*)&pong[lo + 4] = val1;
        }

        pv0 = val0; pv1 = val1;
      }
      pop = op;

      if (j < KSTEP - 1) {
        // lgkm-only barrier: LDS ping/pong visibility without vmcnt drain.
        asm volatile("s_waitcnt lgkmcnt(0)\n\ts_barrier" ::: "memory");
      }
      float* tmp = ping; ping = pong; pong = tmp;
    }

    // Final step's output store.
    if (til) {
      *(float4*)(pop + gofs) = pv0;
      *(float4*)(pop + gofs + 4) = pv1;
    }
  }
#undef CELL
}

extern "C" void kernel_launch(void* const* d_in, const int* in_sizes, int n_in,
                              void* d_out, int out_size, void* d_ws,
                              size_t ws_size, hipStream_t stream) {
  const float* x = (const float*)d_in[0];  // [B, T, 1]
  const float* c = (const float*)d_in[1];  // [192,192]
  const float* b = (const float*)d_in[2];  // [192,192]
  float* out = (float*)d_out;              // [B, T, 192, 192]

  dim3 grid(NXg / TS, NYg / TS, BATCH);  // 8 x 8 x 4 = 256 blocks = 1/CU
  int t0b = 0, t0e = TSTEPS;
  const float* ca = c; const float* ba = b; const float* xa = x; float* oa = out;
  void* args[] = {(void*)&ca, (void*)&ba, (void*)&xa, (void*)&oa,
                  (void*)&t0b, (void*)&t0e};
  hipError_t err = hipLaunchCooperativeKernel(
      (const void*)wave_kernel, grid, dim3(NTHREADS), args, 0, stream);
  if (err != hipSuccess) {
    // Fallback: classic 16-launch path (grid.sync never executes when a
    // launch covers a single phase).
    for (int t0 = 0; t0 < TSTEPS; t0 += KSTEP) {
      wave_kernel<<<grid, NTHREADS, 0, stream>>>(c, b, x, out, t0, t0 + KSTEP);
    }
  }
}

// Round 4
// 624.403 us; speedup vs baseline: 1.2410x; 1.2410x over previous
//
#include <hip/hip_runtime.h>

// WaveCell round-10: ONE cooperative launch, 16 phases x 16 steps, with a
// NEIGHBOR-FLAG PIPELINE instead of grid.sync / kernel boundaries.
// Round-9 evidence: E_phase ~8us, launch boundary ~12us, grid.sync ~35us
// (649us coop vs 318us 16-launch; VALUBusy 5.4%). The phase dependency is
// only 8-neighbor (halo width 16 <= tile 24), and every output address is
// written once and read only one phase later by the 3x3 neighborhood ->
// arbitrary block skew is safe. Protocol per boundary:
//   writer: __syncthreads (per-thread vmcnt drain) -> agent RELEASE store
//           flags[bid]=p+1 (buffer_wbl2 sc1: XCD L2 dirty -> LLC)
//   reader: 8 threads spin on neighbor flags (relaxed agent atomic loads,
//           s_sleep backoff) -> __syncthreads -> agent ACQUIRE fence
//           (buffer_inv sc1) -> halo reload from LLC
// Cooperative launch guarantees co-residency (deadlock safety). Fallback:
// classic 16-launch path (spin/release never fire when a launch covers one
// phase). flags live in d_ws, zeroed each iteration via captured memset.
// Carried: fused 7-op cell, trapezoid row-gating, lgkm-only step barriers,
// pipelined output stores, masked lg==7 shuffle, hoisted coefficients.

#define NXg 192
#define NYg 192
#define BATCH 4
#define TSTEPS 256
#define CELLS (NXg * NYg)

#define TS 24                   // output tile side
#define KSTEP 16                // time steps per phase
#define NPHASE (TSTEPS / KSTEP) // 16
#define EXT 56                  // TS + 2*KSTEP
#define LROWS (EXT + 2)         // rows 1..56 used; 0/57 never read
#define LPITCH 68               // dwords/row: 4 pad | 56 data | 8 pad
#define LSZ (LROWS * LPITCH)
#define NTHREADS 448            // 56 rows x 8 lanes/row = 7 waves

#define SRC_X 96
#define SRC_Y 32

__global__ __launch_bounds__(NTHREADS) void wave_kernel(
    const float* __restrict__ cgp, const float* __restrict__ bgp,
    const float* __restrict__ x, float* __restrict__ out,
    unsigned int* __restrict__ flags, int p0, int p1) {
  __shared__ float buf0[LSZ];
  __shared__ float buf1[LSZ];

  const int tid = threadIdx.x;
  const int lr = tid >> 3;      // local row 0..55
  const int lg = tid & 7;       // 8-wide group in row; lg==7 is the zero lane
  const int bcol = blockIdx.x;  // 0..7
  const int brow = blockIdx.y;  // 0..7
  const int bb = blockIdx.z;    // 0..3
  const int r0 = brow * TS - KSTEP;
  const int c0 = bcol * TS - KSTEP;
  const int obase = bb * TSTEPS * CELLS;
  const float inv_h2 = (float)(1.0 / (2.0 * 1.01 * 1.01 * 1.0e-3 * 1.0e-3));

  const int gr = r0 + lr;
  const int gc = c0 + 8 * lg;  // multiple of 8; never straddles domain edge
  const bool id = (lg < 7) && (gr >= 0) && (gr < NXg) && (gc >= 0) && (gc < NYg);
  const bool til = (lr >= KSTEP) && (lr < KSTEP + TS) && (lg >= 2) && (lg < 5);
  const bool hs = (SRC_X >= r0) && (SRC_X < r0 + EXT) &&
                  (SRC_Y >= c0) && (SRC_Y < c0 + EXT);
  const int gofs = id ? (gr * NYg + gc) : 0;

  // Pipeline handshake identity: own flag slot + (for tid<8) one neighbor.
  const int bid = (bb * 8 + brow) * 8 + bcol;
  int nbr_id = -1;
  if (tid < 8) {
    const int idx = (tid < 4) ? tid : tid + 1;  // skip center of 3x3
    const int nr = brow + idx / 3 - 1;
    const int nc = bcol + idx % 3 - 1;
    if (nr >= 0 && nr < 8 && nc >= 0 && nc < 8)
      nbr_id = (bb * 8 + nr) * 8 + nc;
  }

  const float4 z4 = make_float4(0.f, 0.f, 0.f, 0.f);

  // ---- Loop-invariant: c/b loads + fused coefficients + source mask. ----
  // val = Dc*yc - Ey*yp + G*(sum4 - 4*yc) [+ sm*xt]
  // !id lanes keep Dc=Ey=G=0 -> val identically 0 (zero padding / zero lane).
  float4 Dc0 = z4, Dc1 = z4, Ey0 = z4, Ey1 = z4, G0 = z4, G1 = z4;
  float4 sm0 = z4, sm1 = z4;
  if (id) {
    float4 cv0 = *(const float4*)(cgp + gofs);
    float4 cv1 = *(const float4*)(cgp + gofs + 4);
    float4 bv0 = *(const float4*)(bgp + gofs);
    float4 bv1 = *(const float4*)(bgp + gofs + 4);
    float ai;
    ai = 1.0f / (1.0e6f + 500.0f * bv0.x);
    Dc0.x = 2.0e6f * ai; Ey0.x = (1.0e6f - 500.0f * bv0.x) * ai;
    G0.x = (cv0.x * cv0.x) * inv_h2 * ai;
    ai = 1.0f / (1.0e6f + 500.0f * bv0.y);
    Dc0.y = 2.0e6f * ai; Ey0.y = (1.0e6f - 500.0f * bv0.y) * ai;
    G0.y = (cv0.y * cv0.y) * inv_h2 * ai;
    ai = 1.0f / (1.0e6f + 500.0f * bv0.z);
    Dc0.z = 2.0e6f * ai; Ey0.z = (1.0e6f - 500.0f * bv0.z) * ai;
    G0.z = (cv0.z * cv0.z) * inv_h2 * ai;
    ai = 1.0f / (1.0e6f + 500.0f * bv0.w);
    Dc0.w = 2.0e6f * ai; Ey0.w = (1.0e6f - 500.0f * bv0.w) * ai;
    G0.w = (cv0.w * cv0.w) * inv_h2 * ai;
    ai = 1.0f / (1.0e6f + 500.0f * bv1.x);
    Dc1.x = 2.0e6f * ai; Ey1.x = (1.0e6f - 500.0f * bv1.x) * ai;
    G1.x = (cv1.x * cv1.x) * inv_h2 * ai;
    ai = 1.0f / (1.0e6f + 500.0f * bv1.y);
    Dc1.y = 2.0e6f * ai; Ey1.y = (1.0e6f - 500.0f * bv1.y) * ai;
    G1.y = (cv1.y * cv1.y) * inv_h2 * ai;
    ai = 1.0f / (1.0e6f + 500.0f * bv1.z);
    Dc1.z = 2.0e6f * ai; Ey1.z = (1.0e6f - 500.0f * bv1.z) * ai;
    G1.z = (cv1.z * cv1.z) * inv_h2 * ai;
    ai = 1.0f / (1.0e6f + 500.0f * bv1.w);
    Dc1.w = 2.0e6f * ai; Ey1.w = (1.0e6f - 500.0f * bv1.w) * ai;
    G1.w = (cv1.w * cv1.w) * inv_h2 * ai;
    if (gr == SRC_X) {
      sm0.x = (gc + 0 == SRC_Y) ? 1.0f : 0.0f;
      sm0.y = (gc + 1 == SRC_Y) ? 1.0f : 0.0f;
      sm0.z = (gc + 2 == SRC_Y) ? 1.0f : 0.0f;
      sm0.w = (gc + 3 == SRC_Y) ? 1.0f : 0.0f;
      sm1.x = (gc + 4 == SRC_Y) ? 1.0f : 0.0f;
      sm1.y = (gc + 5 == SRC_Y) ? 1.0f : 0.0f;
      sm1.z = (gc + 6 == SRC_Y) ? 1.0f : 0.0f;
      sm1.w = (gc + 7 == SRC_Y) ? 1.0f : 0.0f;
    }
  }

  const int lo = (lr + 1) * LPITCH + 4 + 8 * lg;

#define CELL(dst, up_, dn_, lf_, rt_, D_, E_, Gc_, y_, p_)              \
  {                                                                     \
    float s_ = fmaf(-4.0f, y_, (up_ + dn_) + (lf_ + rt_));              \
    dst = fmaf(Gc_, s_, fmaf(-E_, p_, D_ * y_));                        \
  }

  for (int p = p0; p < p1; ++p) {
    const int t0 = p * KSTEP;

    if (p > p0) {
      // ---- Acquire side of the pipeline handshake. ----
      if (tid < 8 && nbr_id >= 0) {
        while (__hip_atomic_load(&flags[nbr_id], __ATOMIC_RELAXED,
                                 __HIP_MEMORY_SCOPE_AGENT) < (unsigned)p)
          __builtin_amdgcn_s_sleep(2);
      }
      __syncthreads();
      // Invalidate local caches so halo reads see neighbors' LLC data.
      __builtin_amdgcn_fence(__ATOMIC_ACQUIRE, "agent");
    }

    // ---- Per-phase state reload (halo-extended region, 2 time slices). ----
    float4 yc0 = z4, yc1 = z4, yp0 = z4, yp1 = z4;
    if (id && t0 > 0) {
      yc0 = *(const float4*)(out + obase + (t0 - 1) * CELLS + gofs);
      yc1 = *(const float4*)(out + obase + (t0 - 1) * CELLS + gofs + 4);
      yp0 = *(const float4*)(out + obase + (t0 - 2) * CELLS + gofs);
      yp1 = *(const float4*)(out + obase + (t0 - 2) * CELLS + gofs + 4);
    }
    float xs[KSTEP];
    {
      const float4* xp = (const float4*)(x + bb * TSTEPS + t0);
      float4 a0 = xp[0], a1 = xp[1], a2 = xp[2], a3 = xp[3];
      xs[0] = a0.x; xs[1] = a0.y; xs[2] = a0.z; xs[3] = a0.w;
      xs[4] = a1.x; xs[5] = a1.y; xs[6] = a1.z; xs[7] = a1.w;
      xs[8] = a2.x; xs[9] = a2.y; xs[10] = a2.z; xs[11] = a2.w;
      xs[12] = a3.x; xs[13] = a3.y; xs[14] = a3.z; xs[15] = a3.w;
    }

    // Scatter y(t-1) into buf0 rows 1..56 (guard rows never read).
    *(float4*)&buf0[lo] = yc0;
    *(float4*)&buf0[lo + 4] = yc1;
    asm volatile("s_waitcnt lgkmcnt(0)\n\ts_barrier" ::: "memory");

    float* ping = buf0;
    float* pong = buf1;

    float4 pv0 = z4, pv1 = z4;
    float* pop = out;  // dummy; only used when j>0

#pragma unroll
    for (int j = 0; j < KSTEP; ++j) {
      const float xt = xs[j];
      float* op = out + obase + (t0 + j) * CELLS;

      // Store PREVIOUS step's output now; never drained inside the loop
      // (lgkm-only barriers), drained at the phase-end __syncthreads.
      if (j > 0 && til) {
        *(float4*)(pop + gofs) = pv0;
        *(float4*)(pop + gofs + 4) = pv1;
      }

      // Trapezoid gating: step j only needs rows [j+1, 54-j]; j is
      // compile-time (full unroll) -> dead waves skip via execz.
      const bool alive = (lr >= j + 1) && (lr <= 54 - j);
      if (alive) {
        float lqw = __shfl_up(yc1.w, 1);
        lqw = (lg == 0) ? 0.0f : lqw;       // row's left edge neighbor is 0
        float rqx = __shfl_down(yc0.x, 1);  // lg==6 pulls zero lane -> 0
        rqx = (lg == 7) ? 0.0f : rqx;       // source lane may be exec-masked

        float4 up0 = *(float4*)&ping[lo - LPITCH];
        float4 up1 = *(float4*)&ping[lo - LPITCH + 4];
        float4 dn0 = *(float4*)&ping[lo + LPITCH];
        float4 dn1 = *(float4*)&ping[lo + LPITCH + 4];

        float4 val0, val1;
        CELL(val0.x, up0.x, dn0.x, lqw,    yc0.y, Dc0.x, Ey0.x, G0.x, yc0.x, yp0.x);
        CELL(val0.y, up0.y, dn0.y, yc0.x,  yc0.z, Dc0.y, Ey0.y, G0.y, yc0.y, yp0.y);
        CELL(val0.z, up0.z, dn0.z, yc0.y,  yc0.w, Dc0.z, Ey0.z, G0.z, yc0.z, yp0.z);
        CELL(val0.w, up0.w, dn0.w, yc0.z,  yc1.x, Dc0.w, Ey0.w, G0.w, yc0.w, yp0.w);
        CELL(val1.x, up1.x, dn1.x, yc0.w,  yc1.y, Dc1.x, Ey1.x, G1.x, yc1.x, yp1.x);
        CELL(val1.y, up1.y, dn1.y, yc1.x,  yc1.z, Dc1.y, Ey1.y, G1.y, yc1.y, yp1.y);
        CELL(val1.z, up1.z, dn1.z, yc1.y,  yc1.w, Dc1.z, Ey1.z, G1.z, yc1.z, yp1.z);
        CELL(val1.w, up1.w, dn1.w, yc1.z,  rqx,   Dc1.w, Ey1.w, G1.w, yc1.w, yp1.w);

        if (hs) {  // uniform: only blocks whose EXT tile contains the source
          val0.x = fmaf(sm0.x, xt, val0.x);
          val0.y = fmaf(sm0.y, xt, val0.y);
          val0.z = fmaf(sm0.z, xt, val0.z);
          val0.w = fmaf(sm0.w, xt, val0.w);
          val1.x = fmaf(sm1.x, xt, val1.x);
          val1.y = fmaf(sm1.y, xt, val1.y);
          val1.z = fmaf(sm1.z, xt, val1.z);
          val1.w = fmaf(sm1.w, xt, val1.w);
        }

        yp0 = yc0; yp1 = yc1;
        yc0 = val0; yc1 = val1;

        if (j < KSTEP - 1) {           // final step's LDS state never read
          *(float4*)&pong[lo] = val0;  // lg==7 writes 0 into right pad
          *(float4*)&pong[lo + 4] = val1;
        }

        pv0 = val0; pv1 = val1;
      }
      pop = op;

      if (j < KSTEP - 1) {
        // lgkm-only barrier: LDS ping/pong visibility without vmcnt drain.
        asm volatile("s_waitcnt lgkmcnt(0)\n\ts_barrier" ::: "memory");
      }
      float* tmp = ping; ping = pong; pong = tmp;
    }

    // Final step's output store.
    if (til) {
      *(float4*)(pop + gofs) = pv0;
      *(float4*)(pop + gofs + 4) = pv1;
    }

    if (p + 1 < p1) {
      // ---- Release side of the pipeline handshake. ----
      // __syncthreads: every thread drains its own vmcnt before s_barrier,
      // so all the block's phase-p stores are in L2 when tid 0 proceeds.
      __syncthreads();
      if (tid == 0)
        __hip_atomic_store(&flags[bid], (unsigned)(p + 1), __ATOMIC_RELEASE,
                           __HIP_MEMORY_SCOPE_AGENT);  // wbl2: L2 -> LLC
    }
  }
#undef CELL
}

extern "C" void kernel_launch(void* const* d_in, const int* in_sizes, int n_in,
                              void* d_out, int out_size, void* d_ws,
                              size_t ws_size, hipStream_t stream) {
  const float* x = (const float*)d_in[0];  // [B, T, 1]
  const float* c = (const float*)d_in[1];  // [192,192]
  const float* b = (const float*)d_in[2];  // [192,192]
  float* out = (float*)d_out;              // [B, T, 192, 192]
  unsigned int* flags = (unsigned int*)d_ws;

  // Zero the 256 per-block phase flags (stream-ordered; graph-capturable).
  hipMemsetAsync(flags, 0, 256 * sizeof(unsigned int), stream);

  dim3 grid(NXg / TS, NYg / TS, BATCH);  // 8 x 8 x 4 = 256 blocks = 1/CU
  int p0 = 0, p1 = NPHASE;
  const float* ca = c; const float* ba = b; const float* xa = x; float* oa = out;
  unsigned int* fa = flags;
  void* args[] = {(void*)&ca, (void*)&ba, (void*)&xa, (void*)&oa,
                  (void*)&fa, (void*)&p0, (void*)&p1};
  hipError_t err = hipLaunchCooperativeKernel(
      (const void*)wave_kernel, grid, dim3(NTHREADS), args, 0, stream);
  if (err != hipSuccess) {
    // Fallback: classic 16-launch path (handshake never fires when a launch
    // covers a single phase; visibility via kernel boundaries).
    for (int p = 0; p < NPHASE; ++p) {
      wave_kernel<<<grid, NTHREADS, 0, stream>>>(c, b, x, out, flags, p, p + 1);
    }
  }
}

// Round 5
// 439.810 us; speedup vs baseline: 1.7619x; 1.4197x over previous
//
#include <hip/hip_runtime.h>

// WaveCell round-11: cooperative launch + neighbor-flag pipeline, now with a
// FENCE-FREE handshake. Round-10 showed the flag pipeline's cost (~25us per
// boundary) was dominated by cache maintenance: RELEASE atomic -> buffer_wbl2
// sc1 (full L2 dirty writeback, x32 blocks per XCD) and ACQUIRE fence ->
// buffer_inv sc1 (full L2 invalidate). Fix: output stores are issued as
// device-coherent instructions (global_store_dwordx4 sc0 sc1 = write-through
// past the XCD L2 to LLC -- the same encoding LLVM uses for relaxed
// agent-scope atomic stores). Then:
//   release: __syncthreads (per-thread vmcnt drain => sc1 stores at LLC)
//            + RELAXED agent flag store            [no wbl2]
//   acquire: relaxed flag spin + __syncthreads     [no buffer_inv]
// No stale-line hazard: each phase loads time-slice addresses never before
// touched by this block (fresh tags -> miss to LLC), own stores bypass
// L1/L2-dirty state, flags are atomics (inherently device-coherent).
// Carried: fused 7-op cell, trapezoid row-gating, lgkm-only step barriers,
// pipelined output stores, masked lg==7 shuffle, hoisted coefficients.

#define NXg 192
#define NYg 192
#define BATCH 4
#define TSTEPS 256
#define CELLS (NXg * NYg)

#define TS 24                   // output tile side
#define KSTEP 16                // time steps per phase
#define NPHASE (TSTEPS / KSTEP) // 16
#define EXT 56                  // TS + 2*KSTEP
#define LROWS (EXT + 2)         // rows 1..56 used; 0/57 never read
#define LPITCH 68               // dwords/row: 4 pad | 56 data | 8 pad
#define LSZ (LROWS * LPITCH)
#define NTHREADS 448            // 56 rows x 8 lanes/row = 7 waves

#define SRC_X 96
#define SRC_Y 32

typedef float __attribute__((ext_vector_type(4))) f32x4;

// Device-coherent 16B store: write-through past the XCD L2 to LLC.
__device__ __forceinline__ void store_f4_dc(float* p, float4 v) {
  f32x4 w;
  w.x = v.x; w.y = v.y; w.z = v.z; w.w = v.w;
  asm volatile("global_store_dwordx4 %0, %1, off sc0 sc1"
               :
               : "v"(p), "v"(w)
               : "memory");
}

__global__ __launch_bounds__(NTHREADS) void wave_kernel(
    const float* __restrict__ cgp, const float* __restrict__ bgp,
    const float* __restrict__ x, float* __restrict__ out,
    unsigned int* __restrict__ flags, int p0, int p1) {
  __shared__ float buf0[LSZ];
  __shared__ float buf1[LSZ];

  const int tid = threadIdx.x;
  const int lr = tid >> 3;      // local row 0..55
  const int lg = tid & 7;       // 8-wide group in row; lg==7 is the zero lane
  const int bcol = blockIdx.x;  // 0..7
  const int brow = blockIdx.y;  // 0..7
  const int bb = blockIdx.z;    // 0..3
  const int r0 = brow * TS - KSTEP;
  const int c0 = bcol * TS - KSTEP;
  const int obase = bb * TSTEPS * CELLS;
  const float inv_h2 = (float)(1.0 / (2.0 * 1.01 * 1.01 * 1.0e-3 * 1.0e-3));

  const int gr = r0 + lr;
  const int gc = c0 + 8 * lg;  // multiple of 8; never straddles domain edge
  const bool id = (lg < 7) && (gr >= 0) && (gr < NXg) && (gc >= 0) && (gc < NYg);
  const bool til = (lr >= KSTEP) && (lr < KSTEP + TS) && (lg >= 2) && (lg < 5);
  const bool hs = (SRC_X >= r0) && (SRC_X < r0 + EXT) &&
                  (SRC_Y >= c0) && (SRC_Y < c0 + EXT);
  const int gofs = id ? (gr * NYg + gc) : 0;

  // Pipeline handshake identity: own flag slot + (for tid<8) one neighbor.
  const int bid = (bb * 8 + brow) * 8 + bcol;
  int nbr_id = -1;
  if (tid < 8) {
    const int idx = (tid < 4) ? tid : tid + 1;  // skip center of 3x3
    const int nr = brow + idx / 3 - 1;
    const int nc = bcol + idx % 3 - 1;
    if (nr >= 0 && nr < 8 && nc >= 0 && nc < 8)
      nbr_id = (bb * 8 + nr) * 8 + nc;
  }

  const float4 z4 = make_float4(0.f, 0.f, 0.f, 0.f);

  // ---- Loop-invariant: c/b loads + fused coefficients + source mask. ----
  // val = Dc*yc - Ey*yp + G*(sum4 - 4*yc) [+ sm*xt]
  // !id lanes keep Dc=Ey=G=0 -> val identically 0 (zero padding / zero lane).
  float4 Dc0 = z4, Dc1 = z4, Ey0 = z4, Ey1 = z4, G0 = z4, G1 = z4;
  float4 sm0 = z4, sm1 = z4;
  if (id) {
    float4 cv0 = *(const float4*)(cgp + gofs);
    float4 cv1 = *(const float4*)(cgp + gofs + 4);
    float4 bv0 = *(const float4*)(bgp + gofs);
    float4 bv1 = *(const float4*)(bgp + gofs + 4);
    float ai;
    ai = 1.0f / (1.0e6f + 500.0f * bv0.x);
    Dc0.x = 2.0e6f * ai; Ey0.x = (1.0e6f - 500.0f * bv0.x) * ai;
    G0.x = (cv0.x * cv0.x) * inv_h2 * ai;
    ai = 1.0f / (1.0e6f + 500.0f * bv0.y);
    Dc0.y = 2.0e6f * ai; Ey0.y = (1.0e6f - 500.0f * bv0.y) * ai;
    G0.y = (cv0.y * cv0.y) * inv_h2 * ai;
    ai = 1.0f / (1.0e6f + 500.0f * bv0.z);
    Dc0.z = 2.0e6f * ai; Ey0.z = (1.0e6f - 500.0f * bv0.z) * ai;
    G0.z = (cv0.z * cv0.z) * inv_h2 * ai;
    ai = 1.0f / (1.0e6f + 500.0f * bv0.w);
    Dc0.w = 2.0e6f * ai; Ey0.w = (1.0e6f - 500.0f * bv0.w) * ai;
    G0.w = (cv0.w * cv0.w) * inv_h2 * ai;
    ai = 1.0f / (1.0e6f + 500.0f * bv1.x);
    Dc1.x = 2.0e6f * ai; Ey1.x = (1.0e6f - 500.0f * bv1.x) * ai;
    G1.x = (cv1.x * cv1.x) * inv_h2 * ai;
    ai = 1.0f / (1.0e6f + 500.0f * bv1.y);
    Dc1.y = 2.0e6f * ai; Ey1.y = (1.0e6f - 500.0f * bv1.y) * ai;
    G1.y = (cv1.y * cv1.y) * inv_h2 * ai;
    ai = 1.0f / (1.0e6f + 500.0f * bv1.z);
    Dc1.z = 2.0e6f * ai; Ey1.z = (1.0e6f - 500.0f * bv1.z) * ai;
    G1.z = (cv1.z * cv1.z) * inv_h2 * ai;
    ai = 1.0f / (1.0e6f + 500.0f * bv1.w);
    Dc1.w = 2.0e6f * ai; Ey1.w = (1.0e6f - 500.0f * bv1.w) * ai;
    G1.w = (cv1.w * cv1.w) * inv_h2 * ai;
    if (gr == SRC_X) {
      sm0.x = (gc + 0 == SRC_Y) ? 1.0f : 0.0f;
      sm0.y = (gc + 1 == SRC_Y) ? 1.0f : 0.0f;
      sm0.z = (gc + 2 == SRC_Y) ? 1.0f : 0.0f;
      sm0.w = (gc + 3 == SRC_Y) ? 1.0f : 0.0f;
      sm1.x = (gc + 4 == SRC_Y) ? 1.0f : 0.0f;
      sm1.y = (gc + 5 == SRC_Y) ? 1.0f : 0.0f;
      sm1.z = (gc + 6 == SRC_Y) ? 1.0f : 0.0f;
      sm1.w = (gc + 7 == SRC_Y) ? 1.0f : 0.0f;
    }
  }

  const int lo = (lr + 1) * LPITCH + 4 + 8 * lg;

#define CELL(dst, up_, dn_, lf_, rt_, D_, E_, Gc_, y_, p_)              \
  {                                                                     \
    float s_ = fmaf(-4.0f, y_, (up_ + dn_) + (lf_ + rt_));              \
    dst = fmaf(Gc_, s_, fmaf(-E_, p_, D_ * y_));                        \
  }

  for (int p = p0; p < p1; ++p) {
    const int t0 = p * KSTEP;

    if (p > p0) {
      // ---- Acquire: relaxed spin on neighbor flags; NO cache invalidate.
      // (Safe: this phase's loads hit addresses never previously cached by
      // this block, and the writers' stores were device-coherent sc0 sc1.)
      if (tid < 8 && nbr_id >= 0) {
        while (__hip_atomic_load(&flags[nbr_id], __ATOMIC_RELAXED,
                                 __HIP_MEMORY_SCOPE_AGENT) < (unsigned)p)
          __builtin_amdgcn_s_sleep(2);
      }
      __syncthreads();  // also a compiler memory barrier
    }

    // ---- Per-phase state reload (halo-extended region, 2 time slices). ----
    float4 yc0 = z4, yc1 = z4, yp0 = z4, yp1 = z4;
    if (id && t0 > 0) {
      yc0 = *(const float4*)(out + obase + (t0 - 1) * CELLS + gofs);
      yc1 = *(const float4*)(out + obase + (t0 - 1) * CELLS + gofs + 4);
      yp0 = *(const float4*)(out + obase + (t0 - 2) * CELLS + gofs);
      yp1 = *(const float4*)(out + obase + (t0 - 2) * CELLS + gofs + 4);
    }
    float xs[KSTEP];
    {
      const float4* xp = (const float4*)(x + bb * TSTEPS + t0);
      float4 a0 = xp[0], a1 = xp[1], a2 = xp[2], a3 = xp[3];
      xs[0] = a0.x; xs[1] = a0.y; xs[2] = a0.z; xs[3] = a0.w;
      xs[4] = a1.x; xs[5] = a1.y; xs[6] = a1.z; xs[7] = a1.w;
      xs[8] = a2.x; xs[9] = a2.y; xs[10] = a2.z; xs[11] = a2.w;
      xs[12] = a3.x; xs[13] = a3.y; xs[14] = a3.z; xs[15] = a3.w;
    }

    // Scatter y(t-1) into buf0 rows 1..56 (guard rows never read).
    *(float4*)&buf0[lo] = yc0;
    *(float4*)&buf0[lo + 4] = yc1;
    asm volatile("s_waitcnt lgkmcnt(0)\n\ts_barrier" ::: "memory");

    float* ping = buf0;
    float* pong = buf1;

    float4 pv0 = z4, pv1 = z4;
    float* pop = out;  // dummy; only used when j>0

#pragma unroll
    for (int j = 0; j < KSTEP; ++j) {
      const float xt = xs[j];
      float* op = out + obase + (t0 + j) * CELLS;

      // Store PREVIOUS step's output now (device-coherent, write-through);
      // never drained inside the loop, drained at the phase-end barrier.
      if (j > 0 && til) {
        store_f4_dc(pop + gofs, pv0);
        store_f4_dc(pop + gofs + 4, pv1);
      }

      // Trapezoid gating: step j only needs rows [j+1, 54-j]; j is
      // compile-time (full unroll) -> dead waves skip via execz.
      const bool alive = (lr >= j + 1) && (lr <= 54 - j);
      if (alive) {
        float lqw = __shfl_up(yc1.w, 1);
        lqw = (lg == 0) ? 0.0f : lqw;       // row's left edge neighbor is 0
        float rqx = __shfl_down(yc0.x, 1);  // lg==6 pulls zero lane -> 0
        rqx = (lg == 7) ? 0.0f : rqx;       // source lane may be exec-masked

        float4 up0 = *(float4*)&ping[lo - LPITCH];
        float4 up1 = *(float4*)&ping[lo - LPITCH + 4];
        float4 dn0 = *(float4*)&ping[lo + LPITCH];
        float4 dn1 = *(float4*)&ping[lo + LPITCH + 4];

        float4 val0, val1;
        CELL(val0.x, up0.x, dn0.x, lqw,    yc0.y, Dc0.x, Ey0.x, G0.x, yc0.x, yp0.x);
        CELL(val0.y, up0.y, dn0.y, yc0.x,  yc0.z, Dc0.y, Ey0.y, G0.y, yc0.y, yp0.y);
        CELL(val0.z, up0.z, dn0.z, yc0.y,  yc0.w, Dc0.z, Ey0.z, G0.z, yc0.z, yp0.z);
        CELL(val0.w, up0.w, dn0.w, yc0.z,  yc1.x, Dc0.w, Ey0.w, G0.w, yc0.w, yp0.w);
        CELL(val1.x, up1.x, dn1.x, yc0.w,  yc1.y, Dc1.x, Ey1.x, G1.x, yc1.x, yp1.x);
        CELL(val1.y, up1.y, dn1.y, yc1.x,  yc1.z, Dc1.y, Ey1.y, G1.y, yc1.y, yp1.y);
        CELL(val1.z, up1.z, dn1.z, yc1.y,  yc1.w, Dc1.z, Ey1.z, G1.z, yc1.z, yp1.z);
        CELL(val1.w, up1.w, dn1.w, yc1.z,  rqx,   Dc1.w, Ey1.w, G1.w, yc1.w, yp1.w);

        if (hs) {  // uniform: only blocks whose EXT tile contains the source
          val0.x = fmaf(sm0.x, xt, val0.x);
          val0.y = fmaf(sm0.y, xt, val0.y);
          val0.z = fmaf(sm0.z, xt, val0.z);
          val0.w = fmaf(sm0.w, xt, val0.w);
          val1.x = fmaf(sm1.x, xt, val1.x);
          val1.y = fmaf(sm1.y, xt, val1.y);
          val1.z = fmaf(sm1.z, xt, val1.z);
          val1.w = fmaf(sm1.w, xt, val1.w);
        }

        yp0 = yc0; yp1 = yc1;
        yc0 = val0; yc1 = val1;

        if (j < KSTEP - 1) {           // final step's LDS state never read
          *(float4*)&pong[lo] = val0;  // lg==7 writes 0 into right pad
          *(float4*)&pong[lo + 4] = val1;
        }

        pv0 = val0; pv1 = val1;
      }
      pop = op;

      if (j < KSTEP - 1) {
        // lgkm-only barrier: LDS ping/pong visibility without vmcnt drain.
        asm volatile("s_waitcnt lgkmcnt(0)\n\ts_barrier" ::: "memory");
      }
      float* tmp = ping; ping = pong; pong = tmp;
    }

    // Final step's output store (device-coherent).
    if (til) {
      store_f4_dc(pop + gofs, pv0);
      store_f4_dc(pop + gofs + 4, pv1);
    }

    if (p + 1 < p1) {
      // ---- Release: __syncthreads drains every thread's vmcnt, so all the
      // block's sc0sc1 stores are at LLC; then a RELAXED agent flag store.
      // No wbl2 needed -- nothing dirty in L2 to flush.
      __syncthreads();
      if (tid == 0)
        __hip_atomic_store(&flags[bid], (unsigned)(p + 1), __ATOMIC_RELAXED,
                           __HIP_MEMORY_SCOPE_AGENT);
    }
  }
#undef CELL
}

extern "C" void kernel_launch(void* const* d_in, const int* in_sizes, int n_in,
                              void* d_out, int out_size, void* d_ws,
                              size_t ws_size, hipStream_t stream) {
  const float* x = (const float*)d_in[0];  // [B, T, 1]
  const float* c = (const float*)d_in[1];  // [192,192]
  const float* b = (const float*)d_in[2];  // [192,192]
  float* out = (float*)d_out;              // [B, T, 192, 192]
  unsigned int* flags = (unsigned int*)d_ws;

  // Zero the 256 per-block phase flags (stream-ordered; graph-capturable).
  hipMemsetAsync(flags, 0, 256 * sizeof(unsigned int), stream);

  dim3 grid(NXg / TS, NYg / TS, BATCH);  // 8 x 8 x 4 = 256 blocks = 1/CU
  int p0 = 0, p1 = NPHASE;
  const float* ca = c; const float* ba = b; const float* xa = x; float* oa = out;
  unsigned int* fa = flags;
  void* args[] = {(void*)&ca, (void*)&ba, (void*)&xa, (void*)&oa,
                  (void*)&fa, (void*)&p0, (void*)&p1};
  hipError_t err = hipLaunchCooperativeKernel(
      (const void*)wave_kernel, grid, dim3(NTHREADS), args, 0, stream);
  if (err != hipSuccess) {
    // Fallback: classic 16-launch path (handshake never fires when a launch
    // covers a single phase; visibility via kernel boundaries).
    for (int p = 0; p < NPHASE; ++p) {
      wave_kernel<<<grid, NTHREADS, 0, stream>>>(c, b, x, out, flags, p, p + 1);
    }
  }
}